// Round 1
// baseline (2219.613 us; speedup 1.0000x reference)
//
#include <hip/hip_runtime.h>
#include <hip/hip_bf16.h>

#define TOKENS 2048
#define HIDDEN 2048
#define INTER  5632
#define NEXP   8
#define NPAIR  4096   // TOKENS * TOP_K

typedef __bf16 bf16_t;
typedef bf16_t bf16x8 __attribute__((ext_vector_type(8)));
typedef float  floatx4 __attribute__((ext_vector_type(4)));

#define BM  128
#define BK  32
#define LDK 40      // padded LDS leading dim (elements): 80B rows, 16B-aligned, 2-way-only conflicts
#define BN1 64      // gemm1 N tile (computes gate+up simultaneously)
#define BN2 128     // gemm2 N tile

// ---------------- routing ----------------
__global__ void route_count_k(const int* __restrict__ idx, int* __restrict__ counts) {
    int t = blockIdx.x * blockDim.x + threadIdx.x;
    if (t < NPAIR) atomicAdd(&counts[idx[t]], 1);
}

__global__ void route_scan_k(const int* __restrict__ counts, int* __restrict__ offsets,
                             int* __restrict__ cursor) {
    if (threadIdx.x == 0 && blockIdx.x == 0) {
        int acc = 0;
        for (int e = 0; e < NEXP; ++e) { offsets[e] = acc; cursor[e] = acc; acc += counts[e]; }
    }
}

__global__ void route_place_k(const int* __restrict__ idx, const float* __restrict__ ew,
                              int* __restrict__ cursor, int* __restrict__ tok,
                              float* __restrict__ wt) {
    int t = blockIdx.x * blockDim.x + threadIdx.x;
    if (t < NPAIR) {
        int e = idx[t];
        int pos = atomicAdd(&cursor[e], 1);
        tok[pos] = t >> 1;   // idx is [T][K] flat; token id = t/2
        wt[pos]  = ew[t];
    }
}

// ---------------- GEMM1: H = silu(Xg @ w1) * (Xg @ w3), bf16 out ----------------
__global__ __launch_bounds__(256, 2)
void gemm1_k(const float* __restrict__ x, const float* __restrict__ w1,
             const float* __restrict__ w3, const int* __restrict__ counts,
             const int* __restrict__ offsets, const int* __restrict__ tok,
             bf16_t* __restrict__ H) {
    const int e  = blockIdx.z;
    const int me = counts[e];
    const int m0 = blockIdx.y * BM;
    if (m0 >= me) return;
    const int n0   = blockIdx.x * BN1;
    const int base = offsets[e];

    __shared__ bf16_t As[BM][LDK];
    __shared__ bf16_t Bg[BN1][LDK];
    __shared__ bf16_t Bu[BN1][LDK];

    const int tid = threadIdx.x;

    // A staging: 4 rows/thread, 4 floats each -> 128x32 tile
    const int ar = tid >> 3;          // 0..31
    const int ac = (tid & 7) * 4;     // 0..28
    const float* aptr[4];
    bool aval[4];
#pragma unroll
    for (int i = 0; i < 4; ++i) {
        int row = ar + 32 * i;
        bool v  = (m0 + row) < me;
        aval[i] = v;
        int trow = v ? tok[base + m0 + row] : 0;
        aptr[i] = x + (size_t)trow * HIDDEN + ac;
    }

    // B staging: 32x64 tile each for w1/w3; 2 k-rows per thread, 4 cols
    const int bk = tid >> 4;          // 0..15
    const int bn = (tid & 15) * 4;    // 0..60
    const float* w1p = w1 + (size_t)e * HIDDEN * INTER + (size_t)bk * INTER + n0 + bn;
    const float* w3p = w3 + (size_t)e * HIDDEN * INTER + (size_t)bk * INTER + n0 + bn;

    const int lane = tid & 63;
    const int wave = tid >> 6;
    const int wm   = (wave >> 1) * 64;  // 0 / 64
    const int wn   = (wave & 1) * 32;   // 0 / 32
    const int fr   = lane & 15;
    const int quad = lane >> 4;

    floatx4 accg[4][2], accu[4][2];
#pragma unroll
    for (int i = 0; i < 4; ++i)
#pragma unroll
        for (int j = 0; j < 2; ++j) {
            accg[i][j] = (floatx4){0.f, 0.f, 0.f, 0.f};
            accu[i][j] = (floatx4){0.f, 0.f, 0.f, 0.f};
        }

    for (int k0 = 0; k0 < HIDDEN; k0 += BK) {
        // ---- stage A (fp32 -> bf16) ----
#pragma unroll
        for (int i = 0; i < 4; ++i) {
            floatx4 v = (floatx4){0.f, 0.f, 0.f, 0.f};
            if (aval[i]) v = *(const floatx4*)(aptr[i] + k0);
            union { bf16_t h[4]; unsigned long long u; } p;
            p.h[0] = (bf16_t)v.x; p.h[1] = (bf16_t)v.y;
            p.h[2] = (bf16_t)v.z; p.h[3] = (bf16_t)v.w;
            *(unsigned long long*)&As[ar + 32 * i][ac] = p.u;
        }
        // ---- stage B (fp32 -> bf16, transpose to [n][k]) ----
#pragma unroll
        for (int i = 0; i < 2; ++i) {
            const size_t off = (size_t)(k0 + 16 * i) * INTER;
            floatx4 vg = *(const floatx4*)(w1p + off);
            floatx4 vu = *(const floatx4*)(w3p + off);
            int kr = bk + 16 * i;
            Bg[bn + 0][kr] = (bf16_t)vg.x; Bg[bn + 1][kr] = (bf16_t)vg.y;
            Bg[bn + 2][kr] = (bf16_t)vg.z; Bg[bn + 3][kr] = (bf16_t)vg.w;
            Bu[bn + 0][kr] = (bf16_t)vu.x; Bu[bn + 1][kr] = (bf16_t)vu.y;
            Bu[bn + 2][kr] = (bf16_t)vu.z; Bu[bn + 3][kr] = (bf16_t)vu.w;
        }
        __syncthreads();

        // ---- fragments + MFMA ----
        bf16x8 af[4], bgf[2], buf[2];
#pragma unroll
        for (int i = 0; i < 4; ++i)
            af[i] = *(const bf16x8*)&As[wm + i * 16 + fr][quad * 8];
#pragma unroll
        for (int j = 0; j < 2; ++j) {
            bgf[j] = *(const bf16x8*)&Bg[wn + j * 16 + fr][quad * 8];
            buf[j] = *(const bf16x8*)&Bu[wn + j * 16 + fr][quad * 8];
        }
#pragma unroll
        for (int i = 0; i < 4; ++i)
#pragma unroll
            for (int j = 0; j < 2; ++j) {
                accg[i][j] = __builtin_amdgcn_mfma_f32_16x16x32_bf16(af[i], bgf[j], accg[i][j], 0, 0, 0);
                accu[i][j] = __builtin_amdgcn_mfma_f32_16x16x32_bf16(af[i], buf[j], accu[i][j], 0, 0, 0);
            }
        __syncthreads();
    }

    // ---- epilogue: silu(g)*u -> H (bf16) ----
#pragma unroll
    for (int i = 0; i < 4; ++i) {
#pragma unroll
        for (int r = 0; r < 4; ++r) {
            int mrow = wm + i * 16 + quad * 4 + r;
            if (m0 + mrow < me) {
                size_t hrow = (size_t)(base + m0 + mrow) * INTER;
#pragma unroll
                for (int j = 0; j < 2; ++j) {
                    float g = accg[i][j][r];
                    float u = accu[i][j][r];
                    float s = g / (1.f + __expf(-g));
                    int col = n0 + wn + j * 16 + fr;
                    H[hrow + col] = (bf16_t)(s * u);
                }
            }
        }
    }
}

// ---------------- GEMM2: out[tok] += wt * (H @ w2) ----------------
__global__ __launch_bounds__(256, 2)
void gemm2_k(const bf16_t* __restrict__ H, const float* __restrict__ w2,
             const int* __restrict__ counts, const int* __restrict__ offsets,
             const int* __restrict__ tok, const float* __restrict__ wt,
             float* __restrict__ out) {
    const int e  = blockIdx.z;
    const int me = counts[e];
    const int m0 = blockIdx.y * BM;
    if (m0 >= me) return;
    const int n0   = blockIdx.x * BN2;
    const int base = offsets[e];

    __shared__ bf16_t As[BM][LDK];
    __shared__ bf16_t Bs[BN2][LDK];

    const int tid = threadIdx.x;

    // A staging: H is already bf16 row-major; 2 rows/thread, 8 elems (16B) each
    const int ar = tid >> 2;          // 0..63
    const int ac = (tid & 3) * 8;     // 0..24
    const bf16_t* hptr[2];
    bool aval[2];
#pragma unroll
    for (int i = 0; i < 2; ++i) {
        int row = ar + 64 * i;
        aval[i] = (m0 + row) < me;
        hptr[i] = H + (size_t)(base + m0 + row) * INTER + ac;
    }

    // B staging: 32x128 fp32 -> transpose; kr 0..7 (+8*i), 4 cols
    const int bk = tid >> 5;          // 0..7
    const int bn = (tid & 31) * 4;    // 0..124
    const float* w2p = w2 + (size_t)e * INTER * HIDDEN + (size_t)bk * HIDDEN + n0 + bn;

    const int lane = tid & 63;
    const int wave = tid >> 6;
    const int wm   = (wave >> 1) * 64;
    const int wn   = (wave & 1) * 64;
    const int fr   = lane & 15;
    const int quad = lane >> 4;

    floatx4 acc[4][4];
#pragma unroll
    for (int i = 0; i < 4; ++i)
#pragma unroll
        for (int j = 0; j < 4; ++j) acc[i][j] = (floatx4){0.f, 0.f, 0.f, 0.f};

    for (int k0 = 0; k0 < INTER; k0 += BK) {
#pragma unroll
        for (int i = 0; i < 2; ++i) {
            bf16x8 v = (bf16x8)(bf16_t)0.f;
            if (aval[i]) v = *(const bf16x8*)(hptr[i] + k0);
            *(bf16x8*)&As[ar + 64 * i][ac] = v;
        }
#pragma unroll
        for (int i = 0; i < 4; ++i) {
            floatx4 v = *(const floatx4*)(w2p + (size_t)(k0 + 8 * i) * HIDDEN);
            int kr = bk + 8 * i;
            Bs[bn + 0][kr] = (bf16_t)v.x; Bs[bn + 1][kr] = (bf16_t)v.y;
            Bs[bn + 2][kr] = (bf16_t)v.z; Bs[bn + 3][kr] = (bf16_t)v.w;
        }
        __syncthreads();

        bf16x8 af[4], bf[4];
#pragma unroll
        for (int i = 0; i < 4; ++i) {
            af[i] = *(const bf16x8*)&As[wm + i * 16 + fr][quad * 8];
            bf[i] = *(const bf16x8*)&Bs[wn + i * 16 + fr][quad * 8];
        }
#pragma unroll
        for (int i = 0; i < 4; ++i)
#pragma unroll
            for (int j = 0; j < 4; ++j)
                acc[i][j] = __builtin_amdgcn_mfma_f32_16x16x32_bf16(af[i], bf[j], acc[i][j], 0, 0, 0);
        __syncthreads();
    }

    // epilogue: scaled atomic add into out
#pragma unroll
    for (int i = 0; i < 4; ++i) {
#pragma unroll
        for (int r = 0; r < 4; ++r) {
            int mrow = wm + i * 16 + quad * 4 + r;
            if (m0 + mrow < me) {
                int p = base + m0 + mrow;
                int trow = tok[p];
                float w  = wt[p];
                float* orow = out + (size_t)trow * HIDDEN;
#pragma unroll
                for (int j = 0; j < 4; ++j) {
                    int col = n0 + wn + j * 16 + fr;
                    atomicAdd(&orow[col], w * acc[i][j][r]);
                }
            }
        }
    }
}

extern "C" void kernel_launch(void* const* d_in, const int* in_sizes, int n_in,
                              void* d_out, int out_size, void* d_ws, size_t ws_size,
                              hipStream_t stream) {
    const float* x  = (const float*)d_in[0];
    const float* ew = (const float*)d_in[1];
    const float* w1 = (const float*)d_in[2];
    const float* w2 = (const float*)d_in[3];
    const float* w3 = (const float*)d_in[4];
    const int*  idx = (const int*)d_in[5];
    float* out = (float*)d_out;

    char* ws = (char*)d_ws;
    int*    counts  = (int*)(ws + 0);
    int*    offsets = (int*)(ws + 32);
    int*    cursor  = (int*)(ws + 64);
    int*    tok     = (int*)(ws + 256);
    float*  wt      = (float*)(ws + 256 + NPAIR * 4);
    bf16_t* H       = (bf16_t*)(ws + 65536);

    hipMemsetAsync(counts, 0, 96, stream);
    hipMemsetAsync(out, 0, (size_t)TOKENS * HIDDEN * sizeof(float), stream);

    route_count_k<<<NPAIR / 256, 256, 0, stream>>>(idx, counts);
    route_scan_k<<<1, 64, 0, stream>>>(counts, offsets, cursor);
    route_place_k<<<NPAIR / 256, 256, 0, stream>>>(idx, ew, cursor, tok, wt);

    gemm1_k<<<dim3(INTER / BN1, NPAIR / BM, NEXP), 256, 0, stream>>>(
        x, w1, w3, counts, offsets, tok, H);
    gemm2_k<<<dim3(HIDDEN / BN2, NPAIR / BM, NEXP), 256, 0, stream>>>(
        H, w2, counts, offsets, tok, wt, out);
}